// Round 17
// baseline (4050.886 us; speedup 1.0000x reference)
//
#include <hip/hip_runtime.h>
#include <hip/hip_cooperative_groups.h>

namespace cg = cooperative_groups;

typedef short short8 __attribute__((ext_vector_type(8)));
typedef float f32x4 __attribute__((ext_vector_type(4)));
typedef unsigned u32x4 __attribute__((ext_vector_type(4)));

#define DD 4096
#define KSL 8         // split-K; ks = bid&7 == XCD
#define KSLAB 512     // k-rows per block
#define NT 16         // k-tiles of 32 per block
#define NLAYER 15

__device__ __forceinline__ unsigned short f2bf(float f) {
  unsigned u = __float_as_uint(f);
  u += 0x7FFFu + ((u >> 16) & 1u);   // round-to-nearest-even
  return (unsigned short)(u >> 16);
}
__device__ __forceinline__ float bf2f(unsigned short b) {
  return __uint_as_float(((unsigned)b) << 16);
}

// 4x4 quad transpose across p-lane groups (verified R3-R16)
__device__ __forceinline__ void qtrans(f32x4 v, int p, unsigned& lo, unsigned& hi) {
  unsigned d0 = (unsigned)f2bf(v[0]) | ((unsigned)f2bf(v[1]) << 16);
  unsigned d1 = (unsigned)f2bf(v[2]) | ((unsigned)f2bf(v[3]) << 16);
  unsigned o0 = (unsigned)__shfl_xor((int)d0, 16);
  unsigned o1 = (unsigned)__shfl_xor((int)d1, 16);
  unsigned r0, r1;
  if ((p & 1) == 0) { r0 = (d0 & 0xFFFFu) | (o0 << 16); r1 = (d0 >> 16) | (o0 & 0xFFFF0000u); }
  else              { r0 = (o1 & 0xFFFFu) | (d1 << 16); r1 = (o1 >> 16) | (d1 & 0xFFFF0000u); }
  unsigned q0 = (unsigned)__shfl_xor((int)r0, 32);
  unsigned q1 = (unsigned)__shfl_xor((int)r1, 32);
  if (p < 2) { lo = r0; hi = q0; } else { lo = q1; hi = r1; }
}

// R14 k_gemm body (436us-verified geometry): block (nblk, ks) = [256 m x 128 n],
// k in [ks*512,+512); depth-3 W register pipeline; dense partial layout
// [ks][nblk][256 m][128 nl].
__device__ __forceinline__ void gemm_phase(const unsigned short* __restrict__ A,
                                           const float* __restrict__ W,
                                           unsigned short* __restrict__ part,
                                           int bid, int tid, unsigned char* smem) {
  const int ks   = bid & 7;
  const int nblk = bid >> 3;         // 0..31
  const int n0   = nblk * 128;
  const int lane = tid & 63;
  const int wave = tid >> 6;         // 0..7
  const int l15  = lane & 15;
  const int p    = lane >> 4;        // 0..3
  const int pp   = ((p & 1) << 1) | (p >> 1);
  const int nw   = 4 * l15 + pp;     // transposed n-col within 64-strip

  const int kg0 = wave & 3, ns0 = wave >> 2;
  const float* w0 = W + (size_t)(ks * KSLAB + 8 * kg0 + p) * DD + n0 + ns0 * 64 + 4 * l15;

  const int wm = wave & 3, wn = wave >> 2;   // wave tile [64 m x 64 n]
  const size_t arow = (size_t)(wm * 64 + l15) * 32 + 8 * p;
  const unsigned short* Ab = A + (size_t)ks * 16 * 8192 + arow;

  const f32x4 fz = {0.f, 0.f, 0.f, 0.f};
  f32x4 acc[4][4];
#pragma unroll
  for (int i = 0; i < 4; ++i)
#pragma unroll
    for (int j = 0; j < 4; ++j) acc[i][j] = fz;

  f32x4 wr[3][2];
  short8 ar[2][4];

#define LOADW(T, S)                                                   \
  do {                                                                \
    const float* s_ = w0 + (size_t)(T) * 32 * DD;                     \
    wr[S][0] = *(const f32x4*)s_;                                     \
    wr[S][1] = *(const f32x4*)(s_ + 4 * DD);                          \
  } while (0)

#define LOADA(T, S)                                                   \
  do {                                                                \
    _Pragma("unroll")                                                 \
    for (int mf = 0; mf < 4; ++mf)                                    \
      ar[S][mf] = *(const short8*)(Ab + (size_t)(T) * 8192 + mf * 16 * 32); \
  } while (0)

#define STAGE(S, BUF)                                                 \
  do {                                                                \
    unsigned la, ha, lb, hb;                                          \
    qtrans(wr[S][0], p, la, ha);                                      \
    qtrans(wr[S][1], p, lb, hb);                                      \
    u32x4 v0 = {la, ha, lb, hb};                                      \
    *(u32x4*)(smem + (BUF) * 8192 + kg0 * 2048 + (ns0 * 64 + nw) * 16) = v0; \
  } while (0)

  LOADW(0, 0);
  LOADW(1, 1);
  LOADW(2, 2);
  LOADA(0, 0);
  STAGE(0, 0);
  __syncthreads();

#pragma unroll
  for (int it = 0; it < NT; ++it) {
    if (it + 1 < NT) LOADA(it + 1, (it + 1) & 1);
    if (it + 1 < NT) STAGE((it + 1) % 3, (it + 1) & 1);
    if (it + 3 < NT) LOADW(it + 3, (it + 3) % 3);
    const unsigned char* bbase = smem + (it & 1) * 8192 + p * 2048 + (wn * 64 + l15) * 16;
#pragma unroll
    for (int nf = 0; nf < 4; ++nf) {
      short8 bf = *(const short8*)(bbase + nf * 256);
#pragma unroll
      for (int mf = 0; mf < 4; ++mf)
        acc[mf][nf] = __builtin_amdgcn_mfma_f32_16x16x32_bf16(ar[it & 1][mf], bf,
                                                              acc[mf][nf], 0, 0, 0);
    }
    __syncthreads();
  }
#undef LOADW
#undef LOADA
#undef STAGE

  unsigned short* pl = part + ((size_t)(ks * 32 + nblk)) * (256 * 128);
#pragma unroll
  for (int mf = 0; mf < 4; ++mf)
#pragma unroll
    for (int nf = 0; nf < 4; ++nf) {
      f32x4 a = acc[mf][nf], o;
#pragma unroll
      for (int j = 0; j < 4; ++j) o[j] = __shfl_xor(a[j], 1);
      if ((l15 & 1) == 0) {
        const int nl = wn * 64 + nf * 16 + l15;
        const int rb = wm * 64 + mf * 16 + 4 * p;
#pragma unroll
        for (int j = 0; j < 4; ++j) {
          unsigned pk = (unsigned)f2bf(a[j]) | ((unsigned)f2bf(o[j]) << 16);
          *(unsigned*)((char*)pl + ((size_t)(rb + j) * 128 + nl) * 2) = pk;
        }
      }
    }
}

// R14 k_reduce body: sum 8 bf16 dense partials + bias, relu -> bf16 blocked h
// (+ fp32 out on last layer). t = global thread id, 8 elems/thread.
__device__ __forceinline__ void reduce_phase(const unsigned short* __restrict__ part,
                                             const float* __restrict__ bias,
                                             unsigned short* __restrict__ hout,
                                             float* __restrict__ fout, int t) {
  const size_t e = (size_t)t * 8;
  const int m = (int)(e >> 12), n = (int)(e & (DD - 1));
  const int nblk = n >> 7, nl = n & 127;
  const size_t pofs = ((size_t)nblk * 256 + m) * 128 + nl;
  float s[8] = {0.f, 0.f, 0.f, 0.f, 0.f, 0.f, 0.f, 0.f};
#pragma unroll
  for (int ks = 0; ks < KSL; ++ks) {
    short8 v = *(const short8*)(part + (size_t)ks * (32 * 256 * 128) + pofs);
#pragma unroll
    for (int j = 0; j < 8; ++j) s[j] += bf2f((unsigned short)v[j]);
  }
  f32x4 b0 = *(const f32x4*)(bias + n);
  f32x4 b1 = *(const f32x4*)(bias + n + 4);
#pragma unroll
  for (int j = 0; j < 4; ++j) {
    s[j]     = fmaxf(s[j] + b0[j], 0.f);
    s[4 + j] = fmaxf(s[4 + j] + b1[j], 0.f);
  }
  short8 o;
#pragma unroll
  for (int j = 0; j < 8; ++j) o[j] = (short)f2bf(s[j]);
  *(short8*)(hout + (size_t)(n >> 5) * 8192 + m * 32 + (n & 31)) = o;
  if (fout) {
    f32x4 o0, o1;
#pragma unroll
    for (int j = 0; j < 4; ++j) { o0[j] = s[j]; o1[j] = s[4 + j]; }
    float* dst = fout + e;
    *(f32x4*)dst = o0;
    *(f32x4*)(dst + 4) = o1;
  }
}

// Single cooperative kernel: convert -> 15 x (gemm -> sync -> reduce -> sync).
// Replaces 31 graph nodes with 1; fences give cross-XCD visibility at each sync
// (same work a kernel boundary performs). 256 blocks x 512 thr, 1/CU co-resident.
__global__ __launch_bounds__(512) void k_fused(const float* __restrict__ x,
                                               const float* __restrict__ W,
                                               const float* __restrict__ bias,
                                               float* __restrict__ out,
                                               unsigned short* __restrict__ h0,
                                               unsigned short* __restrict__ h1,
                                               unsigned short* __restrict__ part) {
  __shared__ __align__(16) unsigned char smem[16384];
  cg::grid_group grid = cg::this_grid();
  const int bid = blockIdx.x, tid = threadIdx.x;
  const int t = bid * 512 + tid;        // 0..131071

  // phase 0: fp32 x -> bf16 h0 blocked [k>>5][m 256][k&31] (8 elems/thread)
  {
    const size_t e = (size_t)t * 8;
    const int m = (int)(e >> 12), n = (int)(e & (DD - 1));
    f32x4 a = *(const f32x4*)(x + e);
    f32x4 c = *(const f32x4*)(x + e + 4);
    short8 v;
#pragma unroll
    for (int j = 0; j < 4; ++j) { v[j] = (short)f2bf(a[j]); v[4 + j] = (short)f2bf(c[j]); }
    *(short8*)(h0 + (size_t)(n >> 5) * 8192 + m * 32 + (n & 31)) = v;
  }
  __threadfence();
  grid.sync();

  unsigned short* hc = h0;
  unsigned short* hn = h1;
#pragma unroll 1
  for (int l = 0; l < NLAYER; ++l) {
    gemm_phase(hc, W + (size_t)l * DD * DD, part, bid, tid, smem);
    __threadfence();                 // release: partials -> device scope
    grid.sync();
    __threadfence();                 // acquire: drop stale partial lines
    reduce_phase(part, bias + (size_t)l * DD, hn,
                 (l == NLAYER - 1) ? out : nullptr, t);
    __threadfence();                 // release: h(l+1) -> device scope
    grid.sync();
    __threadfence();                 // acquire for next layer's A reads
    unsigned short* tmp = hc; hc = hn; hn = tmp;
  }
}

extern "C" void kernel_launch(void* const* d_in, const int* in_sizes, int n_in,
                              void* d_out, int out_size, void* d_ws, size_t ws_size,
                              hipStream_t stream) {
  const float* x = (const float*)d_in[0];
  const float* W = (const float*)d_in[1];
  const float* b = (const float*)d_in[2];
  float* out = (float*)d_out;

  char* ws = (char*)d_ws;
  unsigned short* h0 = (unsigned short*)ws;                 // 2 MB bf16 blocked
  unsigned short* h1 = (unsigned short*)(ws + (1 << 21));   // 2 MB
  unsigned short* part = (unsigned short*)(ws + (1 << 22)); // 8 x 2 MB bf16 partials

  void* args[] = {(void*)&x, (void*)&W, (void*)&b, (void*)&out,
                  (void*)&h0, (void*)&h1, (void*)&part};
  hipLaunchCooperativeKernel((const void*)k_fused, dim3(256), dim3(512),
                             args, 0, stream);
}

// Round 18
// 436.720 us; speedup vs baseline: 9.2757x; 9.2757x over previous
//
#include <hip/hip_runtime.h>

typedef short short8 __attribute__((ext_vector_type(8)));
typedef float f32x4 __attribute__((ext_vector_type(4)));
typedef unsigned u32x4 __attribute__((ext_vector_type(4)));

#define DD 4096
#define KSL 8         // split-K; ks = bid&7 == XCD; partials 8 x 2MB bf16
#define KSLAB 512     // k-rows per block
#define NT 16         // k-tiles of 32 per block
#define NLAYER 15

__device__ __forceinline__ unsigned short f2bf(float f) {
  unsigned u = __float_as_uint(f);
  u += 0x7FFFu + ((u >> 16) & 1u);   // round-to-nearest-even
  return (unsigned short)(u >> 16);
}
__device__ __forceinline__ float bf2f(unsigned short b) {
  return __uint_as_float(((unsigned)b) << 16);
}

// fp32 x [256][4096] -> bf16 h blocked [k>>5][m 256][k&31]
__global__ __launch_bounds__(256) void k_tobf16(const float* __restrict__ x,
                                                unsigned short* __restrict__ h) {
  const size_t e = ((size_t)blockIdx.x * 256 + threadIdx.x) * 8;
  const int m = (int)(e >> 12), n = (int)(e & (DD - 1));
  f32x4 a = *(const f32x4*)(x + e);
  f32x4 b = *(const f32x4*)(x + e + 4);
  short8 v;
#pragma unroll
  for (int j = 0; j < 4; ++j) { v[j] = (short)f2bf(a[j]); v[4 + j] = (short)f2bf(b[j]); }
  *(short8*)(h + (size_t)(n >> 5) * 8192 + m * 32 + (n & 31)) = v;
}

// 4x4 quad transpose across p-lane groups (verified R3-R16)
__device__ __forceinline__ void qtrans(f32x4 v, int p, unsigned& lo, unsigned& hi) {
  unsigned d0 = (unsigned)f2bf(v[0]) | ((unsigned)f2bf(v[1]) << 16);
  unsigned d1 = (unsigned)f2bf(v[2]) | ((unsigned)f2bf(v[3]) << 16);
  unsigned o0 = (unsigned)__shfl_xor((int)d0, 16);
  unsigned o1 = (unsigned)__shfl_xor((int)d1, 16);
  unsigned r0, r1;
  if ((p & 1) == 0) { r0 = (d0 & 0xFFFFu) | (o0 << 16); r1 = (d0 >> 16) | (o0 & 0xFFFF0000u); }
  else              { r0 = (o1 & 0xFFFFu) | (d1 << 16); r1 = (o1 >> 16) | (d1 & 0xFFFF0000u); }
  unsigned q0 = (unsigned)__shfl_xor((int)r0, 32);
  unsigned q1 = (unsigned)__shfl_xor((int)r1, 32);
  if (p < 2) { lo = r0; hi = q0; } else { lo = q1; hi = r1; }
}

// Split-K GEMM partial (R13 structure): block (nblk, ks) = [256 m x 128 n],
// k in [ks*512,+512). Depth-3 W register pipeline; DENSE partial layout
// [ks][nblk][256 m][128 nl] (block-contiguous 256KB writes).
__global__ __launch_bounds__(512, 2) void k_gemm(const unsigned short* __restrict__ A,
                                                 const float* __restrict__ W,
                                                 unsigned short* __restrict__ part) {
  __shared__ __align__(16) unsigned char smem[16384];  // 2 x 8KB W-frag buffers
  const int bid  = blockIdx.x;
  const int ks   = bid & 7;          // == XCD under round-robin dispatch
  const int nblk = bid >> 3;         // 0..31
  const int n0   = nblk * 128;
  const int tid  = threadIdx.x;
  const int lane = tid & 63;
  const int wave = tid >> 6;         // 0..7
  const int l15  = lane & 15;
  const int p    = lane >> 4;        // 0..3
  const int pp   = ((p & 1) << 1) | (p >> 1);
  const int nw   = 4 * l15 + pp;     // transposed n-col within 64-strip

  // W staging role: one (kg, ns) per wave; kg = 8-k group 0..3, ns = 64-col strip 0..1
  const int kg0 = wave & 3, ns0 = wave >> 2;
  const float* w0 = W + (size_t)(ks * KSLAB + 8 * kg0 + p) * DD + n0 + ns0 * 64 + 4 * l15;

  // compute decomposition: 4m x 2n waves, wave tile [64 m x 64 n]
  const int wm = wave & 3, wn = wave >> 2;
  const size_t arow = (size_t)(wm * 64 + l15) * 32 + 8 * p;
  const unsigned short* Ab = A + (size_t)ks * 16 * 8192 + arow;

  const f32x4 fz = {0.f, 0.f, 0.f, 0.f};
  f32x4 acc[4][4];
#pragma unroll
  for (int i = 0; i < 4; ++i)
#pragma unroll
    for (int j = 0; j < 4; ++j) acc[i][j] = fz;

  f32x4 wr[3][2];      // depth-3 slots: [slot][rows p, p+4]
  short8 ar[2][4];     // [slot][mf]

#define LOADW(T, S)                                                   \
  do {                                                                \
    const float* s_ = w0 + (size_t)(T) * 32 * DD;                     \
    wr[S][0] = *(const f32x4*)s_;                                     \
    wr[S][1] = *(const f32x4*)(s_ + 4 * DD);                          \
  } while (0)

#define LOADA(T, S)                                                   \
  do {                                                                \
    _Pragma("unroll")                                                 \
    for (int mf = 0; mf < 4; ++mf)                                    \
      ar[S][mf] = *(const short8*)(Ab + (size_t)(T) * 8192 + mf * 16 * 32); \
  } while (0)

#define STAGE(S, BUF)                                                 \
  do {                                                                \
    unsigned la, ha, lb, hb;                                          \
    qtrans(wr[S][0], p, la, ha);                                      \
    qtrans(wr[S][1], p, lb, hb);                                      \
    u32x4 v0 = {la, ha, lb, hb};                                      \
    *(u32x4*)(smem + (BUF) * 8192 + kg0 * 2048 + (ns0 * 64 + nw) * 16) = v0; \
  } while (0)

  // prologue: 3 W tiles issued, A tile 0, stage tile 0 -> buf 0
  LOADW(0, 0);
  LOADW(1, 1);
  LOADW(2, 2);
  LOADA(0, 0);
  STAGE(0, 0);
  __syncthreads();

#pragma unroll
  for (int it = 0; it < NT; ++it) {
    if (it + 1 < NT) LOADA(it + 1, (it + 1) & 1);
    if (it + 1 < NT) STAGE((it + 1) % 3, (it + 1) & 1);   // slot loaded >=2 iters ago
    if (it + 3 < NT) LOADW(it + 3, (it + 3) % 3);         // refill freed slot
    const unsigned char* bbase = smem + (it & 1) * 8192 + p * 2048 + (wn * 64 + l15) * 16;
#pragma unroll
    for (int nf = 0; nf < 4; ++nf) {
      short8 bf = *(const short8*)(bbase + nf * 256);
#pragma unroll
      for (int mf = 0; mf < 4; ++mf)
        acc[mf][nf] = __builtin_amdgcn_mfma_f32_16x16x32_bf16(ar[it & 1][mf], bf,
                                                              acc[mf][nf], 0, 0, 0);
    }
    __syncthreads();
  }
#undef LOADW
#undef LOADA
#undef STAGE

  // DENSE bf16 partial write: block-own region [ks][nblk][256 m][128 nl]
  unsigned short* pl = part + ((size_t)(ks * 32 + nblk)) * (256 * 128);
#pragma unroll
  for (int mf = 0; mf < 4; ++mf)
#pragma unroll
    for (int nf = 0; nf < 4; ++nf) {
      f32x4 a = acc[mf][nf], o;
#pragma unroll
      for (int j = 0; j < 4; ++j) o[j] = __shfl_xor(a[j], 1);
      if ((l15 & 1) == 0) {
        const int nl = wn * 64 + nf * 16 + l15;            // 0..127 block-local
        const int rb = wm * 64 + mf * 16 + 4 * p;
#pragma unroll
        for (int j = 0; j < 4; ++j) {
          unsigned pk = (unsigned)f2bf(a[j]) | ((unsigned)f2bf(o[j]) << 16);
          *(unsigned*)((char*)pl + ((size_t)(rb + j) * 128 + nl) * 2) = pk;
        }
      }
    }
}

// sum 8 bf16 partials (dense blocked layout) + bias, relu -> bf16 blocked h
// (+ fp32 out on last layer)
__global__ __launch_bounds__(256) void k_reduce(const unsigned short* __restrict__ part,
                                                const float* __restrict__ bias,
                                                unsigned short* __restrict__ hout,
                                                float* __restrict__ fout) {
  const size_t e = ((size_t)blockIdx.x * 256 + threadIdx.x) * 8;
  const int m = (int)(e >> 12), n = (int)(e & (DD - 1));
  const int nblk = n >> 7, nl = n & 127;
  const size_t pofs = ((size_t)nblk * 256 + m) * 128 + nl;   // + ks*32*256*128
  float s[8] = {0.f, 0.f, 0.f, 0.f, 0.f, 0.f, 0.f, 0.f};
#pragma unroll
  for (int ks = 0; ks < KSL; ++ks) {
    short8 v = *(const short8*)(part + (size_t)ks * (32 * 256 * 128) + pofs);
#pragma unroll
    for (int j = 0; j < 8; ++j) s[j] += bf2f((unsigned short)v[j]);
  }
  f32x4 b0 = *(const f32x4*)(bias + n);
  f32x4 b1 = *(const f32x4*)(bias + n + 4);
#pragma unroll
  for (int j = 0; j < 4; ++j) {
    s[j]     = fmaxf(s[j] + b0[j], 0.f);
    s[4 + j] = fmaxf(s[4 + j] + b1[j], 0.f);
  }
  short8 o;
#pragma unroll
  for (int j = 0; j < 8; ++j) o[j] = (short)f2bf(s[j]);
  *(short8*)(hout + (size_t)(n >> 5) * 8192 + m * 32 + (n & 31)) = o;
  if (fout) {
    f32x4 o0, o1;
#pragma unroll
    for (int j = 0; j < 4; ++j) { o0[j] = s[j]; o1[j] = s[4 + j]; }
    float* dst = fout + e;
    *(f32x4*)dst = o0;
    *(f32x4*)(dst + 4) = o1;
  }
}

extern "C" void kernel_launch(void* const* d_in, const int* in_sizes, int n_in,
                              void* d_out, int out_size, void* d_ws, size_t ws_size,
                              hipStream_t stream) {
  const float* x = (const float*)d_in[0];
  const float* W = (const float*)d_in[1];
  const float* b = (const float*)d_in[2];
  float* out = (float*)d_out;

  char* ws = (char*)d_ws;
  unsigned short* h0 = (unsigned short*)ws;                 // 2 MB bf16 blocked
  unsigned short* h1 = (unsigned short*)(ws + (1 << 21));   // 2 MB
  unsigned short* part = (unsigned short*)(ws + (1 << 22)); // 8 x 2 MB bf16 partials

  k_tobf16<<<512, 256, 0, stream>>>(x, h0);
  unsigned short* hc = h0;
  unsigned short* hn = h1;
  for (int l = 0; l < NLAYER; ++l) {
    const bool last = (l == NLAYER - 1);
    k_gemm<<<256, 512, 0, stream>>>(hc, W + (size_t)l * DD * DD, part);
    k_reduce<<<512, 256, 0, stream>>>(part, b + (size_t)l * DD, hn,
                                      last ? out : nullptr);
    unsigned short* t = hc; hc = hn; hn = t;
  }
}